// Round 9
// baseline (15331.303 us; speedup 1.0000x reference)
//
#include <hip/hip_runtime.h>
#include <hip/hip_bf16.h>
#include <hip/hip_cooperative_groups.h>

namespace cg = cooperative_groups;

typedef _Float16 fp16_t;
typedef _Float16 v8h __attribute__((ext_vector_type(8)));
typedef float    v4f __attribute__((ext_vector_type(4)));

#define RELAX_LR 0.3f

// async global->LDS, 16B per lane. LDS dest = wave-uniform base + lane*16.
__device__ __forceinline__ void async_cp16(const void* g, void* l) {
    __builtin_amdgcn_global_load_lds(
        (const __attribute__((address_space(1))) void*)g,
        (__attribute__((address_space(3))) void*)l, 16, 0, 0);
}

struct Params {
    const fp16_t *xb, *rxb;
    const fp16_t *WbT0, *WbT1, *WbT2, *WbT3;   // [N][K] transposed weights
    const fp16_t *Wb1, *Wb2, *Wb3;             // [K][N] original-layout weights
    fp16_t *s1b, *s2b, *s3b, *s4b;             // fp16 states (GEMM operands)
    float  *s1f, *s2f, *s3f, *s4f;             // fp32 states (recurrence)
    const float *b1, *b2, *b3, *b4p;
    fp16_t *part;                              // fp16 split-K partials (16 MB)
    float  *out;
};

// ---------------------------------------------------------------------------
// Whole relaxation in ONE cooperative kernel: 104 GEMM phases + 104 reduce
// phases + out-copy, separated by grid.sync() (kills ~600us of launch gaps).
// GEMM: BM=128 x BN=128 x BK=64 split-K into fp16 partials, 4 waves of 64x64
// (4x4 16x16x32 f16 MFMA), double-buffered LDS (64 KB -> exactly 2 blocks/CU
// = the full 512-block cooperative grid). Math is identical to the r8
// pipeline; layer-3 split-K is rebalanced 1024/1024/512/512 so all 512
// blocks work every phase.
// ---------------------------------------------------------------------------
__global__ __launch_bounds__(256, 2) void eqprop_kernel(Params P)
{
    cg::grid_group grid = cg::this_grid();

    __shared__ __align__(16) fp16_t As[2][2][128][32];  // [stage][khalf][row][col]
    __shared__ __align__(16) fp16_t Bs[2][2][128][32];

    const int tid  = threadIdx.x;
    const int lane = tid & 63;
    const int w    = tid >> 6;          // wave 0..3
    const int wm   = w >> 1;            // m-half (64 rows)
    const int wn   = w & 1;             // n-half (64 cols)
    const int quad = lane >> 4;
    const int lrow = lane & 15;
    const int blk  = blockIdx.x;        // 0..511
    const int sr   = lane >> 2;         // staging row within 16-row group
    const int sc   = (lane & 3) * 8;    // staging col (fp16)

    // phases 0..3 = feedforward init layers 1..4; then 25 sweeps x 4 layers.
    for (int ph = 0; ph < 104; ++ph) {
        const int is_init = (ph < 4);
        const int l = is_init ? ph : ((ph - 4) & 3);

        // ---- block decode (all branches block-uniform) ----
        int bn, bm, z, Ntot;
        if (l < 3) { bn = blk & 15; bm = (blk >> 4) & 7; z = blk >> 7; Ntot = 2048; }
        else       { bn = blk & 7;  bm = (blk >> 3) & 7; z = blk >> 6; Ntot = 1024; }

        // ---- section select: concatenated K-space, chunk never crosses the
        //      section boundary ----
        const fp16_t *A, *Bt; int stride, koff, CK;
        if (is_init) {
            switch (l) {
                case 0:  A = P.xb;  Bt = P.WbT0; break;
                case 1:  A = P.s1b; Bt = P.WbT1; break;
                case 2:  A = P.s2b; Bt = P.WbT2; break;
                default: A = P.s3b; Bt = P.WbT3; break;
            }
            stride = 2048;
            CK = (l == 3) ? 256 : 512;
            koff = z * CK;
        } else {
            switch (l) {
                case 0:
                    if (z < 2) { A = P.rxb; Bt = P.WbT0; } else { A = P.s2b; Bt = P.Wb1; }
                    stride = 2048; CK = 1024; koff = (z & 1) * 1024; break;
                case 1:
                    if (z < 2) { A = P.s1b; Bt = P.WbT1; } else { A = P.s3b; Bt = P.Wb2; }
                    stride = 2048; CK = 1024; koff = (z & 1) * 1024; break;
                case 2:
                    if (z < 2) { A = P.s2b; Bt = P.WbT2; stride = 2048; CK = 1024; koff = z * 1024; }
                    else       { A = P.s4b; Bt = P.Wb3;  stride = 1024; CK = 512;  koff = (z - 2) * 512; }
                    break;
                default:
                    A = P.s3b; Bt = P.WbT3; stride = 2048; CK = 256; koff = z * 256; break;
            }
        }

        // ---- GEMM into fp16 partial slice z ----
        {
            const fp16_t* ag = A  + (size_t)(bm * 128 + 32 * w + sr) * stride + koff + sc;
            const fp16_t* bg = Bt + (size_t)(bn * 128 + 32 * w + sr) * stride + koff + sc;
            const size_t st16 = (size_t)16 * stride;

            v4f acc[4][4] = {};
            const int iters = CK >> 6;           // BK = 64

            auto stage = [&](int buf, int kb) {
                const fp16_t* a0 = ag + kb;
                const fp16_t* b0 = bg + kb;
                async_cp16(a0,             &As[buf][0][32 * w     ][0]);
                async_cp16(a0 + st16,      &As[buf][0][32 * w + 16][0]);
                async_cp16(a0 + 32,        &As[buf][1][32 * w     ][0]);
                async_cp16(a0 + 32 + st16, &As[buf][1][32 * w + 16][0]);
                async_cp16(b0,             &Bs[buf][0][32 * w     ][0]);
                async_cp16(b0 + st16,      &Bs[buf][0][32 * w + 16][0]);
                async_cp16(b0 + 32,        &Bs[buf][1][32 * w     ][0]);
                async_cp16(b0 + 32 + st16, &Bs[buf][1][32 * w + 16][0]);
            };

            stage(0, 0);

            for (int it = 0; it < iters; ++it) {
                __syncthreads();   // drains vmcnt -> buf (it&1) ready
                if (it + 1 < iters) stage((it + 1) & 1, (it + 1) * 64);
                const int cur = it & 1;
                #pragma unroll
                for (int h = 0; h < 2; ++h) {
                    v8h af[4], bv[4];
                    #pragma unroll
                    for (int fm = 0; fm < 4; ++fm)
                        af[fm] = *(const v8h*)&As[cur][h][wm * 64 + fm * 16 + lrow][quad * 8];
                    #pragma unroll
                    for (int fn = 0; fn < 4; ++fn)
                        bv[fn] = *(const v8h*)&Bs[cur][h][wn * 64 + fn * 16 + lrow][quad * 8];
                    #pragma unroll
                    for (int fm = 0; fm < 4; ++fm)
                        #pragma unroll
                        for (int fn = 0; fn < 4; ++fn)
                            acc[fm][fn] = __builtin_amdgcn_mfma_f32_16x16x32_f16(
                                af[fm], bv[fn], acc[fm][fn], 0, 0, 0);
                }
            }

            // C/D layout: col = lane&15, row = quad*4 + reg.
            fp16_t* po = P.part + (size_t)z * 1024 * Ntot;
            const int rowbase = bm * 128 + wm * 64 + quad * 4;
            const int colbase = bn * 128 + wn * 64;
            #pragma unroll
            for (int fn = 0; fn < 4; ++fn) {
                const int col = colbase + fn * 16 + lrow;
                #pragma unroll
                for (int fm = 0; fm < 4; ++fm) {
                    const int row = rowbase + fm * 16;
                    #pragma unroll
                    for (int r = 0; r < 4; ++r)
                        po[(size_t)(row + r) * Ntot + col] = (fp16_t)acc[fm][fn][r];
                }
            }
        }

        grid.sync();   // partials visible device-wide

        // ---- reduce: sum nz slices + bias, init/update + clip, dual write ----
        {
            const int nz = (l == 3) ? 8 : 4;
            const float *bias, *sof; float *of; fp16_t *ob;
            switch (l) {
                case 0:  bias = P.b1;  sof = P.s1f; of = P.s1f; ob = P.s1b; break;
                case 1:  bias = P.b2;  sof = P.s2f; of = P.s2f; ob = P.s2b; break;
                case 2:  bias = P.b3;  sof = P.s3f; of = P.s3f; ob = P.s3b; break;
                default: bias = P.b4p; sof = P.s4f; of = P.s4f; ob = P.s4b; break;
            }
            const size_t slice = (size_t)1024 * Ntot;
            const int perblk = (int)(slice >> 3) >> 9;        // total8 / 512 blocks
            const int hi = (blk + 1) * perblk;
            for (int idx = blk * perblk + tid; idx < hi; idx += 256) {
                const size_t e = (size_t)idx * 8;
                float v[8];
                {
                    const v8h p0 = *(const v8h*)(P.part + e);
                    #pragma unroll
                    for (int j = 0; j < 8; ++j) v[j] = (float)p0[j];
                }
                for (int zz = 1; zz < nz; ++zz) {
                    const v8h pp = *(const v8h*)(P.part + (size_t)zz * slice + e);
                    #pragma unroll
                    for (int j = 0; j < 8; ++j) v[j] += (float)pp[j];
                }
                const int col = (int)e & (Ntot - 1);
                const float4 b0 = *(const float4*)(bias + col);
                const float4 b1v = *(const float4*)(bias + col + 4);
                v[0] += b0.x;  v[1] += b0.y;  v[2] += b0.z;  v[3] += b0.w;
                v[4] += b1v.x; v[5] += b1v.y; v[6] += b1v.z; v[7] += b1v.w;
                if (!is_init) {
                    const float4 s0 = *(const float4*)(sof + e);
                    const float4 s1 = *(const float4*)(sof + e + 4);
                    const float so[8] = {s0.x, s0.y, s0.z, s0.w, s1.x, s1.y, s1.z, s1.w};
                    #pragma unroll
                    for (int j = 0; j < 8; ++j) v[j] = so[j] + RELAX_LR * (v[j] - so[j]);
                }
                #pragma unroll
                for (int j = 0; j < 8; ++j) v[j] = fminf(fmaxf(v[j], 0.f), 1.f);
                float4 o0 = {v[0], v[1], v[2], v[3]};
                float4 o1 = {v[4], v[5], v[6], v[7]};
                *(float4*)(of + e)     = o0;
                *(float4*)(of + e + 4) = o1;
                v8h h;
                #pragma unroll
                for (int j = 0; j < 8; ++j) h[j] = (fp16_t)v[j];
                *(v8h*)(ob + e) = h;
            }
        }

        grid.sync();   // states visible before next layer's GEMM
    }

    // ---- strip padding into d_out [1024,1000] ----
    for (int i = blk * 256 + tid; i < 1024 * 1000; i += 512 * 256) {
        const int row = i / 1000;
        const int col = i - row * 1000;
        P.out[i] = P.s4f[(size_t)row * 1024 + col];
    }
}

// fp32 W [R,C] -> fp16 Wb [Rp,Cp] (optional) + fp16 WbT [Cp,Rp], zero-padded.
__global__ void conv_w_kernel(const float* __restrict__ W, int R, int C,
                              fp16_t* Wb, fp16_t* __restrict__ WbT,
                              int Rp, int Cp)
{
    __shared__ float t[32][33];
    const int tx = threadIdx.x & 31;
    const int ty = threadIdx.x >> 5;   // 0..7
    const int r0 = blockIdx.y * 32;
    const int c0 = blockIdx.x * 32;
    #pragma unroll
    for (int i = 0; i < 4; ++i) {
        const int r = r0 + ty + i * 8;
        const int c = c0 + tx;
        float v = 0.f;
        if (r < R && c < C) v = W[(size_t)r * C + c];
        t[ty + i * 8][tx] = v;
    }
    __syncthreads();
    if (Wb) {
        #pragma unroll
        for (int i = 0; i < 4; ++i) {
            const int r = r0 + ty + i * 8;
            const int c = c0 + tx;
            if (r < Rp && c < Cp) Wb[(size_t)r * Cp + c] = (fp16_t)t[ty + i * 8][tx];
        }
    }
    #pragma unroll
    for (int i = 0; i < 4; ++i) {
        const int cc = c0 + ty + i * 8;
        const int rr = r0 + tx;
        if (cc < Cp && rr < Rp) WbT[(size_t)cc * Rp + rr] = (fp16_t)t[tx][ty + i * 8];
    }
}

__global__ void conv_x_kernel(const float* __restrict__ x,
                              fp16_t* __restrict__ xb, fp16_t* __restrict__ rxb, int n)
{
    const int i = blockIdx.x * blockDim.x + threadIdx.x;
    if (i < n) {
        const float v = x[i];
        xb[i]  = (fp16_t)v;
        rxb[i] = (fp16_t)fminf(fmaxf(v, 0.f), 1.f);
    }
}

__global__ void pad_b4_kernel(const float* __restrict__ b4, float* __restrict__ b4p)
{
    const int i = blockIdx.x * blockDim.x + threadIdx.x;
    if (i < 1024) b4p[i] = (i < 1000) ? b4[i] : 0.f;
}

extern "C" void kernel_launch(void* const* d_in, const int* in_sizes, int n_in,
                              void* d_out, int out_size, void* d_ws, size_t ws_size,
                              hipStream_t stream)
{
    const float* x  = (const float*)d_in[0];
    const float* W0 = (const float*)d_in[1];
    const float* W1 = (const float*)d_in[2];
    const float* W2 = (const float*)d_in[3];
    const float* W3 = (const float*)d_in[4];
    const float* b1 = (const float*)d_in[5];
    const float* b2 = (const float*)d_in[6];
    const float* b3 = (const float*)d_in[7];
    const float* b4 = (const float*)d_in[8];

    char* p = (char*)d_ws;
    auto alloc = [&](size_t bytes) {
        char* q = p;
        p += (bytes + 255) & ~(size_t)255;
        return q;
    };

    Params P;
    P.xb   = (fp16_t*)alloc((size_t)1024 * 2048 * 2);
    P.rxb  = (fp16_t*)alloc((size_t)1024 * 2048 * 2);
    P.Wb1  = (fp16_t*)alloc((size_t)2048 * 2048 * 2);
    P.Wb2  = (fp16_t*)alloc((size_t)2048 * 2048 * 2);
    P.Wb3  = (fp16_t*)alloc((size_t)2048 * 1024 * 2);   // padded cols
    P.WbT0 = (fp16_t*)alloc((size_t)2048 * 2048 * 2);
    P.WbT1 = (fp16_t*)alloc((size_t)2048 * 2048 * 2);
    P.WbT2 = (fp16_t*)alloc((size_t)2048 * 2048 * 2);
    P.WbT3 = (fp16_t*)alloc((size_t)1024 * 2048 * 2);   // padded rows
    P.s1f  = (float*)alloc((size_t)1024 * 2048 * 4);
    P.s2f  = (float*)alloc((size_t)1024 * 2048 * 4);
    P.s3f  = (float*)alloc((size_t)1024 * 2048 * 4);
    P.s4f  = (float*)alloc((size_t)1024 * 1024 * 4);
    P.s1b  = (fp16_t*)alloc((size_t)1024 * 2048 * 2);
    P.s2b  = (fp16_t*)alloc((size_t)1024 * 2048 * 2);
    P.s3b  = (fp16_t*)alloc((size_t)1024 * 2048 * 2);
    P.s4b  = (fp16_t*)alloc((size_t)1024 * 1024 * 2);
    P.b4p  = (float*)alloc(1024 * 4);
    P.part = (fp16_t*)alloc((size_t)4 * 1024 * 2048 * 2); // 16 MB, reused
    P.b1 = b1; P.b2 = b2; P.b3 = b3;
    P.out = (float*)d_out;
    (void)ws_size; (void)in_sizes; (void)n_in; (void)out_size;

    // --- setup conversions ---
    conv_x_kernel<<<(1024 * 2048 + 255) / 256, 256, 0, stream>>>(
        x, (fp16_t*)P.xb, (fp16_t*)P.rxb, 1024 * 2048);
    pad_b4_kernel<<<4, 256, 0, stream>>>(b4, (float*)P.b4p);
    conv_w_kernel<<<dim3(64, 64), 256, 0, stream>>>(W0, 2048, 2048, nullptr, (fp16_t*)P.WbT0, 2048, 2048);
    conv_w_kernel<<<dim3(64, 64), 256, 0, stream>>>(W1, 2048, 2048, (fp16_t*)P.Wb1, (fp16_t*)P.WbT1, 2048, 2048);
    conv_w_kernel<<<dim3(64, 64), 256, 0, stream>>>(W2, 2048, 2048, (fp16_t*)P.Wb2, (fp16_t*)P.WbT2, 2048, 2048);
    conv_w_kernel<<<dim3(32, 64), 256, 0, stream>>>(W3, 2048, 1000, (fp16_t*)P.Wb3, (fp16_t*)P.WbT3, 2048, 1024);

    // --- the whole relaxation: one cooperative launch, 512 blocks = 2/CU ---
    void* args[] = { &P };
    hipLaunchCooperativeKernel((const void*)eqprop_kernel,
                               dim3(512), dim3(256), args, 0, stream);
}

// Round 10
// 2852.754 us; speedup vs baseline: 5.3742x; 5.3742x over previous
//
#include <hip/hip_runtime.h>
#include <hip/hip_bf16.h>

typedef _Float16 fp16_t;
typedef _Float16 v8h __attribute__((ext_vector_type(8)));
typedef float    v4f __attribute__((ext_vector_type(4)));

#define RELAX_LR 0.3f

// async global->LDS, 16B per lane. LDS dest = wave-uniform base + lane*16.
__device__ __forceinline__ void async_cp16(const void* g, void* l) {
    __builtin_amdgcn_global_load_lds(
        (const __attribute__((address_space(1))) void*)g,
        (__attribute__((address_space(3))) void*)l, 16, 0, 0);
}

// ---------------------------------------------------------------------------
// Split-K GEMM into fp16 partials (fp32 MFMA accumulate, one rounding at
// store). Fwd section: z<nz1 -> A1*B1t^T chunk z*CK1; bwd: A2*B2t^T chunk
// (z-nz1)*CK2. Tile BM=128 x BN=128 x BK=64, 4 waves of 64x64 (4x4 16x16x32
// f16 MFMA), double-buffered LDS (64 KB -> 2 blocks/CU), 1 barrier/BK-iter.
// 1-D grid of 512, XCD-swizzled decode: linear id % 8 == XCD (round-robin
// heuristic); each XCD gets ONE z-chunk with 8 bn x 8 bm -> per-XCD working
// set = A(z) 2MB + B-tiles 2MB = 4MB = one L2. Correctness is
// decode-independent (pure bijection).
// ---------------------------------------------------------------------------
__global__ __launch_bounds__(256, 2) void gemm_splitk_kernel(
    const fp16_t* __restrict__ A1, const fp16_t* __restrict__ B1t, int K1, int CK1, int nz1,
    const fp16_t* __restrict__ A2, const fp16_t* __restrict__ B2t, int K2s, int CK2,
    fp16_t* __restrict__ part, int Ntot)
{
    __shared__ __align__(16) fp16_t As[2][2][128][32];  // [stage][khalf][row][col]
    __shared__ __align__(16) fp16_t Bs[2][2][128][32];

    const int tid  = threadIdx.x;
    const int lane = tid & 63;
    const int w    = tid >> 6;         // wave 0..3
    const int wm   = w >> 1;           // m-half (64 rows)
    const int wn   = w & 1;            // n-half (64 cols)
    const int quad = lane >> 4;
    const int lrow = lane & 15;

    // swizzled decode: blk%8 = XCD; c = (bn,z) combo pinned to one XCD.
    const int blk  = blockIdx.x;
    const int low3 = blk & 7;
    const int g    = blk >> 3;
    const int bm   = g & 7;
    const int c    = (g >> 3) * 8 + low3;   // 0..63
    int bn, z;
    if (Ntot == 2048) { bn = c >> 2; z = c & 3; }   // 16 bn x 4 z
    else              { bn = c >> 3; z = c & 7; }   // 8 bn x 8 z

    const fp16_t *A, *Bt; int stride, koff, CK;
    if (z < nz1) { A = A1; Bt = B1t; stride = K1;  CK = CK1; koff = z * CK1; }
    else         { A = A2; Bt = B2t; stride = K2s; CK = CK2; koff = (z - nz1) * CK2; }

    // staging: each cp16 = 16 rows x 32 fp16 (1 KB/wave), lane -> (row=lane/4,
    // col=(lane&3)*8) matches LDS base + lane*16. Wave w owns rows
    // [32w,32w+32) of A and B for both khalves: 8 cp16/wave per stage.
    const int sr = lane >> 2;
    const int sc = (lane & 3) * 8;
    const fp16_t* ag = A  + (size_t)(bm * 128 + 32 * w + sr) * stride + koff + sc;
    const fp16_t* bg = Bt + (size_t)(bn * 128 + 32 * w + sr) * stride + koff + sc;
    const size_t st16 = (size_t)16 * stride;

    v4f acc[4][4] = {};
    const int iters = CK >> 6;         // BK = 64

    auto stage = [&](int buf, int kb) {
        const fp16_t* a0 = ag + kb;
        const fp16_t* b0 = bg + kb;
        async_cp16(a0,             &As[buf][0][32 * w     ][0]);
        async_cp16(a0 + st16,      &As[buf][0][32 * w + 16][0]);
        async_cp16(a0 + 32,        &As[buf][1][32 * w     ][0]);
        async_cp16(a0 + 32 + st16, &As[buf][1][32 * w + 16][0]);
        async_cp16(b0,             &Bs[buf][0][32 * w     ][0]);
        async_cp16(b0 + st16,      &Bs[buf][0][32 * w + 16][0]);
        async_cp16(b0 + 32,        &Bs[buf][1][32 * w     ][0]);
        async_cp16(b0 + 32 + st16, &Bs[buf][1][32 * w + 16][0]);
    };

    stage(0, 0);                       // prologue: tile 0 -> buffer 0

    for (int it = 0; it < iters; ++it) {
        __syncthreads();   // drains vmcnt -> buf (it&1) ready; prior ds_reads done
        if (it + 1 < iters) stage((it + 1) & 1, (it + 1) * 64);
        const int cur = it & 1;
        #pragma unroll
        for (int h = 0; h < 2; ++h) {
            v8h af[4], bv[4];
            #pragma unroll
            for (int fm = 0; fm < 4; ++fm)
                af[fm] = *(const v8h*)&As[cur][h][wm * 64 + fm * 16 + lrow][quad * 8];
            #pragma unroll
            for (int fn = 0; fn < 4; ++fn)
                bv[fn] = *(const v8h*)&Bs[cur][h][wn * 64 + fn * 16 + lrow][quad * 8];
            #pragma unroll
            for (int fm = 0; fm < 4; ++fm)
                #pragma unroll
                for (int fn = 0; fn < 4; ++fn)
                    acc[fm][fn] = __builtin_amdgcn_mfma_f32_16x16x32_f16(
                        af[fm], bv[fn], acc[fm][fn], 0, 0, 0);
        }
    }

    // write fp16 partials. C/D layout: col = lane&15, row = quad*4 + reg.
    fp16_t* po = part + (size_t)z * 1024 * Ntot;
    const int rowbase = bm * 128 + wm * 64 + quad * 4;
    const int colbase = bn * 128 + wn * 64;
    #pragma unroll
    for (int fn = 0; fn < 4; ++fn) {
        const int col = colbase + fn * 16 + lrow;
        #pragma unroll
        for (int fm = 0; fm < 4; ++fm) {
            const int row = rowbase + fm * 16;
            #pragma unroll
            for (int r = 0; r < 4; ++r)
                po[(size_t)(row + r) * Ntot + col] = (fp16_t)acc[fm][fn][r];
        }
    }
}

// ---------------------------------------------------------------------------
// Sum nz fp16 partial slices (fp32 accumulate) + bias, init/update + clip,
// fp16 state write (states are fp16-only: operand rounding already dominates
// the error budget; recurrence is contractive so fp16 s_old adds ~1e-3).
// 8 elements/thread, 16B loads. s_old may alias outb (same-thread RMW).
// ---------------------------------------------------------------------------
__global__ __launch_bounds__(256) void reduce_update_kernel(
    const fp16_t* __restrict__ part, int nz,
    const float* __restrict__ bias, const fp16_t* s_old,
    fp16_t* outb, int Ntot, int do_update, int total8)
{
    const int i = blockIdx.x * 256 + threadIdx.x;
    if (i >= total8) return;
    const size_t e = (size_t)i * 8;

    float v[8];
    {
        const v8h p0 = *(const v8h*)(part + e);
        #pragma unroll
        for (int j = 0; j < 8; ++j) v[j] = (float)p0[j];
    }
    for (int z = 1; z < nz; ++z) {
        const v8h p = *(const v8h*)(part + (size_t)z * 1024 * Ntot + e);
        #pragma unroll
        for (int j = 0; j < 8; ++j) v[j] += (float)p[j];
    }
    const int col = (int)e & (Ntot - 1);
    const float4 b0 = *(const float4*)(bias + col);
    const float4 b1 = *(const float4*)(bias + col + 4);
    v[0] += b0.x; v[1] += b0.y; v[2] += b0.z; v[3] += b0.w;
    v[4] += b1.x; v[5] += b1.y; v[6] += b1.z; v[7] += b1.w;
    if (do_update) {
        const v8h so = *(const v8h*)(s_old + e);
        #pragma unroll
        for (int j = 0; j < 8; ++j) {
            const float s = (float)so[j];
            v[j] = s + RELAX_LR * (v[j] - s);
        }
    }
    v8h h;
    #pragma unroll
    for (int j = 0; j < 8; ++j) h[j] = (fp16_t)fminf(fmaxf(v[j], 0.f), 1.f);
    *(v8h*)(outb + e) = h;
}

// fp32 W [R,C] -> fp16 Wb [Rp,Cp] (optional) + fp16 WbT [Cp,Rp], zero-padded.
__global__ void conv_w_kernel(const float* __restrict__ W, int R, int C,
                              fp16_t* Wb, fp16_t* __restrict__ WbT,
                              int Rp, int Cp)
{
    __shared__ float t[32][33];
    const int tx = threadIdx.x & 31;
    const int ty = threadIdx.x >> 5;   // 0..7
    const int r0 = blockIdx.y * 32;
    const int c0 = blockIdx.x * 32;
    #pragma unroll
    for (int i = 0; i < 4; ++i) {
        const int r = r0 + ty + i * 8;
        const int c = c0 + tx;
        float v = 0.f;
        if (r < R && c < C) v = W[(size_t)r * C + c];
        t[ty + i * 8][tx] = v;
    }
    __syncthreads();
    if (Wb) {
        #pragma unroll
        for (int i = 0; i < 4; ++i) {
            const int r = r0 + ty + i * 8;
            const int c = c0 + tx;
            if (r < Rp && c < Cp) Wb[(size_t)r * Cp + c] = (fp16_t)t[ty + i * 8][tx];
        }
    }
    #pragma unroll
    for (int i = 0; i < 4; ++i) {
        const int cc = c0 + ty + i * 8;
        const int rr = r0 + tx;
        if (cc < Cp && rr < Rp) WbT[(size_t)cc * Rp + rr] = (fp16_t)t[tx][ty + i * 8];
    }
}

__global__ void conv_x_kernel(const float* __restrict__ x,
                              fp16_t* __restrict__ xb, fp16_t* __restrict__ rxb, int n)
{
    const int i = blockIdx.x * blockDim.x + threadIdx.x;
    if (i < n) {
        const float v = x[i];
        xb[i]  = (fp16_t)v;
        rxb[i] = (fp16_t)fminf(fmaxf(v, 0.f), 1.f);
    }
}

__global__ void pad_b4_kernel(const float* __restrict__ b4, float* __restrict__ b4p)
{
    const int i = blockIdx.x * blockDim.x + threadIdx.x;
    if (i < 1024) b4p[i] = (i < 1000) ? b4[i] : 0.f;
}

__global__ void out_copy_kernel(const fp16_t* __restrict__ s4b, float* __restrict__ out)
{
    const int i = blockIdx.x * blockDim.x + threadIdx.x;
    if (i < 1024 * 1000) {
        const int row = i / 1000;
        const int col = i - row * 1000;
        out[i] = (float)s4b[(size_t)row * 1024 + col];
    }
}

extern "C" void kernel_launch(void* const* d_in, const int* in_sizes, int n_in,
                              void* d_out, int out_size, void* d_ws, size_t ws_size,
                              hipStream_t stream)
{
    const float* x  = (const float*)d_in[0];
    const float* W0 = (const float*)d_in[1];
    const float* W1 = (const float*)d_in[2];
    const float* W2 = (const float*)d_in[3];
    const float* W3 = (const float*)d_in[4];
    const float* b1 = (const float*)d_in[5];
    const float* b2 = (const float*)d_in[6];
    const float* b3 = (const float*)d_in[7];
    const float* b4 = (const float*)d_in[8];
    float* out = (float*)d_out;

    char* p = (char*)d_ws;
    auto alloc = [&](size_t bytes) {
        char* q = p;
        p += (bytes + 255) & ~(size_t)255;
        return q;
    };

    fp16_t* xb   = (fp16_t*)alloc((size_t)1024 * 2048 * 2);
    fp16_t* rxb  = (fp16_t*)alloc((size_t)1024 * 2048 * 2);
    fp16_t* Wb1  = (fp16_t*)alloc((size_t)2048 * 2048 * 2);
    fp16_t* Wb2  = (fp16_t*)alloc((size_t)2048 * 2048 * 2);
    fp16_t* Wb3  = (fp16_t*)alloc((size_t)2048 * 1024 * 2);   // padded cols
    fp16_t* WbT0 = (fp16_t*)alloc((size_t)2048 * 2048 * 2);
    fp16_t* WbT1 = (fp16_t*)alloc((size_t)2048 * 2048 * 2);
    fp16_t* WbT2 = (fp16_t*)alloc((size_t)2048 * 2048 * 2);
    fp16_t* WbT3 = (fp16_t*)alloc((size_t)1024 * 2048 * 2);   // padded rows
    fp16_t* s1b  = (fp16_t*)alloc((size_t)1024 * 2048 * 2);
    fp16_t* s2b  = (fp16_t*)alloc((size_t)1024 * 2048 * 2);
    fp16_t* s3b  = (fp16_t*)alloc((size_t)1024 * 2048 * 2);
    fp16_t* s4b  = (fp16_t*)alloc((size_t)1024 * 1024 * 2);
    float*  b4p  = (float*)alloc(1024 * 4);
    fp16_t* part = (fp16_t*)alloc((size_t)4 * 1024 * 2048 * 2); // 16 MB, reused
    (void)ws_size; (void)in_sizes; (void)n_in; (void)out_size;

    // --- setup conversions ---
    conv_x_kernel<<<(1024 * 2048 + 255) / 256, 256, 0, stream>>>(x, xb, rxb, 1024 * 2048);
    pad_b4_kernel<<<4, 256, 0, stream>>>(b4, b4p);
    conv_w_kernel<<<dim3(64, 64), 256, 0, stream>>>(W0, 2048, 2048, nullptr, WbT0, 2048, 2048);
    conv_w_kernel<<<dim3(64, 64), 256, 0, stream>>>(W1, 2048, 2048, Wb1, WbT1, 2048, 2048);
    conv_w_kernel<<<dim3(64, 64), 256, 0, stream>>>(W2, 2048, 2048, Wb2, WbT2, 2048, 2048);
    conv_w_kernel<<<dim3(32, 64), 256, 0, stream>>>(W3, 2048, 1000, Wb3, WbT3, 2048, 1024);

    const dim3 blk(256);
    const dim3 g512(512);               // all GEMMs: 512 blocks, swizzled decode
    const int t8_2048 = 1024 * 2048 / 8;
    const int t8_1024 = 1024 * 1024 / 8;
    const int rg2048 = t8_2048 / 256;   // 1024 blocks
    const int rg1024 = t8_1024 / 256;   // 512 blocks

    // --- feedforward init: s_l = clip(s_{l-1} @ W_{l-1} + b_l) ---
    gemm_splitk_kernel<<<g512, blk, 0, stream>>>(xb,  WbT0, 2048, 512, 4, nullptr, nullptr, 0, 0, part, 2048);
    reduce_update_kernel<<<rg2048, blk, 0, stream>>>(part, 4, b1, nullptr, s1b, 2048, 0, t8_2048);
    gemm_splitk_kernel<<<g512, blk, 0, stream>>>(s1b, WbT1, 2048, 512, 4, nullptr, nullptr, 0, 0, part, 2048);
    reduce_update_kernel<<<rg2048, blk, 0, stream>>>(part, 4, b2, nullptr, s2b, 2048, 0, t8_2048);
    gemm_splitk_kernel<<<g512, blk, 0, stream>>>(s2b, WbT2, 2048, 512, 4, nullptr, nullptr, 0, 0, part, 2048);
    reduce_update_kernel<<<rg2048, blk, 0, stream>>>(part, 4, b3, nullptr, s3b, 2048, 0, t8_2048);
    gemm_splitk_kernel<<<g512, blk, 0, stream>>>(s3b, WbT3, 2048, 256, 8, nullptr, nullptr, 0, 0, part, 1024);
    reduce_update_kernel<<<rg1024, blk, 0, stream>>>(part, 8, b4p, nullptr, s4b, 1024, 0, t8_1024);

    // --- 25 Gauss-Seidel sweeps (states post-rho => rho identity on them) ---
    for (int it = 0; it < 25; ++it) {
        // layer 1: rho(x)@W0 (K=2048, 2x1024) + s2@W1^T (K=2048, 2x1024)
        gemm_splitk_kernel<<<g512, blk, 0, stream>>>(rxb, WbT0, 2048, 1024, 2, s2b, Wb1, 2048, 1024, part, 2048);
        reduce_update_kernel<<<rg2048, blk, 0, stream>>>(part, 4, b1, s1b, s1b, 2048, 1, t8_2048);
        // layer 2: s1@W1 + s3@W2^T
        gemm_splitk_kernel<<<g512, blk, 0, stream>>>(s1b, WbT1, 2048, 1024, 2, s3b, Wb2, 2048, 1024, part, 2048);
        reduce_update_kernel<<<rg2048, blk, 0, stream>>>(part, 4, b2, s2b, s2b, 2048, 1, t8_2048);
        // layer 3: s2@W2 (2x1024) + s4@W3^T (K=1024, 2x512) — balanced z=4
        gemm_splitk_kernel<<<g512, blk, 0, stream>>>(s2b, WbT2, 2048, 1024, 2, s4b, Wb3, 1024, 512, part, 2048);
        reduce_update_kernel<<<rg2048, blk, 0, stream>>>(part, 4, b3, s3b, s3b, 2048, 1, t8_2048);
        // layer 4: s3@W3 (K=2048, 8x256)
        gemm_splitk_kernel<<<g512, blk, 0, stream>>>(s3b, WbT3, 2048, 256, 8, nullptr, nullptr, 0, 0, part, 1024);
        reduce_update_kernel<<<rg1024, blk, 0, stream>>>(part, 8, b4p, s4b, s4b, 1024, 1, t8_1024);
    }

    // --- strip padding into d_out [1024,1000] ---
    out_copy_kernel<<<(1024 * 1000 + 255) / 256, 256, 0, stream>>>(s4b, out);
}